// Round 1
// baseline (74.037 us; speedup 1.0000x reference)
//
#include <hip/hip_runtime.h>
#include <math.h>

#define DDIM 2048
#define KP 8

__device__ __forceinline__ float gelu_f(float x) {
    // tanh-approx GELU; tanh(y) = 1 - 2/(exp(2y)+1) (overflow-safe form)
    float y = 0.7978845608028654f * (x + 0.044715f * x * x * x);
    float t = __expf(2.0f * y);
    float th = 1.0f - 2.0f / (t + 1.0f);
    return 0.5f * x * (1.0f + th);
}

__device__ __forceinline__ float wave_reduce_add(float v) {
#pragma unroll
    for (int m = 32; m >= 1; m >>= 1) v += __shfl_xor(v, m, 64);
    return v;
}

// Prologue: inv_pn[k] = 1 / max(||protos_k||, eps)
__global__ void proto_norm_kernel(const float* __restrict__ protos,
                                  float* __restrict__ inv_pn) {
    const int k = blockIdx.x;
    const int tid = threadIdx.x;
    const float* p = protos + k * DDIM;
    float4 a = reinterpret_cast<const float4*>(p)[tid];
    float4 b = reinterpret_cast<const float4*>(p)[tid + 256];
    float ss = a.x * a.x + a.y * a.y + a.z * a.z + a.w * a.w
             + b.x * b.x + b.y * b.y + b.z * b.z + b.w * b.w;
    ss = wave_reduce_add(ss);
    __shared__ float red[4];
    const int wave = tid >> 6, lane = tid & 63;
    if (lane == 0) red[wave] = ss;
    __syncthreads();
    if (tid == 0) {
        float s = red[0] + red[1] + red[2] + red[3];
        inv_pn[k] = 1.0f / fmaxf(sqrtf(s), 1e-12f);
    }
}

__global__ __launch_bounds__(256, 4)
void fused_gate_kernel(const float* __restrict__ x,
                       const float* __restrict__ protos,
                       const float* __restrict__ lt,
                       const float* __restrict__ lg,
                       const float* __restrict__ lb,
                       const float* __restrict__ inv_pn,
                       float* __restrict__ out, int nrows) {
    const int tid = threadIdx.x;
    const int wave = tid >> 6, lane = tid & 63;

    const float tau = __expf(lt[0]);
    const float gamma = __expf(lg[0]);
    const float alpha = 1.0f / (1.0f + __expf(-lb[0]));
    const float inv_tau = 1.0f / tau;
    const float logK_div_tau = logf(8.0f) * inv_tau;

    // Hoist protos into registers: lane covers columns [4*tid,4*tid+4) and
    // [1024+4*tid, 1024+4*tid+4). 64 VGPRs total for 8 protos.
    float4 pr0[KP], pr1[KP];
#pragma unroll
    for (int k = 0; k < KP; ++k) {
        pr0[k] = reinterpret_cast<const float4*>(protos + k * DDIM)[tid];
        pr1[k] = reinterpret_cast<const float4*>(protos + k * DDIM)[tid + 256];
    }
    float ipn[KP];
#pragma unroll
    for (int k = 0; k < KP; ++k) ipn[k] = inv_pn[k];

    __shared__ float red[4][12];
    __shared__ float gateS;

    for (int row = blockIdx.x; row < nrows; row += gridDim.x) {
        const float* xr = x + (size_t)row * DDIM;
        float4 a = reinterpret_cast<const float4*>(xr)[tid];
        float4 b = reinterpret_cast<const float4*>(xr)[tid + 256];

        float4 g0, g1;
        g0.x = gelu_f(a.x); g0.y = gelu_f(a.y); g0.z = gelu_f(a.z); g0.w = gelu_f(a.w);
        g1.x = gelu_f(b.x); g1.y = gelu_f(b.y); g1.z = gelu_f(b.z); g1.w = gelu_f(b.w);

        float vals[9];
        vals[8] = g0.x * g0.x + g0.y * g0.y + g0.z * g0.z + g0.w * g0.w
                + g1.x * g1.x + g1.y * g1.y + g1.z * g1.z + g1.w * g1.w;
#pragma unroll
        for (int k = 0; k < KP; ++k) {
            vals[k] = g0.x * pr0[k].x + g0.y * pr0[k].y + g0.z * pr0[k].z + g0.w * pr0[k].w
                    + g1.x * pr1[k].x + g1.y * pr1[k].y + g1.z * pr1[k].z + g1.w * pr1[k].w;
        }
#pragma unroll
        for (int i = 0; i < 9; ++i) vals[i] = wave_reduce_add(vals[i]);

        if (lane == 0) {
#pragma unroll
            for (int i = 0; i < 9; ++i) red[wave][i] = vals[i];
        }
        __syncthreads();
        if (tid == 0) {
            float s[9];
#pragma unroll
            for (int i = 0; i < 9; ++i)
                s[i] = red[0][i] + red[1][i] + red[2][i] + red[3][i];
            float invn = 1.0f / fmaxf(sqrtf(s[8]), 1e-12f);
            float z[KP];
            float m = -1e30f;
#pragma unroll
            for (int k = 0; k < KP; ++k) {
                z[k] = s[k] * invn * ipn[k] * tau;
                m = fmaxf(m, z[k]);
            }
            float e = 0.0f;
#pragma unroll
            for (int k = 0; k < KP; ++k) e += __expf(z[k] - m);
            float lse = m + __logf(e);
            float sms = lse * inv_tau - logK_div_tau;
            float nov = __expf(-gamma * sms);
            gateS = 1.0f - alpha + alpha * nov;
        }
        __syncthreads();
        const float gate = gateS;

        float* orow = out + (size_t)row * DDIM;
        float4 o0, o1;
        o0.x = g0.x * gate; o0.y = g0.y * gate; o0.z = g0.z * gate; o0.w = g0.w * gate;
        o1.x = g1.x * gate; o1.y = g1.y * gate; o1.z = g1.z * gate; o1.w = g1.w * gate;
        reinterpret_cast<float4*>(orow)[tid] = o0;
        reinterpret_cast<float4*>(orow)[tid + 256] = o1;
    }
}

extern "C" void kernel_launch(void* const* d_in, const int* in_sizes, int n_in,
                              void* d_out, int out_size, void* d_ws, size_t ws_size,
                              hipStream_t stream) {
    const float* x = (const float*)d_in[0];
    const float* protos = (const float*)d_in[1];
    const float* lt = (const float*)d_in[2];
    const float* lg = (const float*)d_in[3];
    const float* lb = (const float*)d_in[4];
    float* out = (float*)d_out;
    float* inv_pn = (float*)d_ws;

    const int nrows = in_sizes[0] / DDIM;

    proto_norm_kernel<<<KP, 256, 0, stream>>>(protos, inv_pn);

    int blocks = nrows < 2048 ? nrows : 2048;
    fused_gate_kernel<<<blocks, 256, 0, stream>>>(x, protos, lt, lg, lb, inv_pn,
                                                  out, nrows);
}